// Round 17
// baseline (40.883 us; speedup 1.0000x reference)
//
#include <hip/hip_runtime.h>

// Lucas-Kanade optical flow v17 = v13's schedule at 4 cols/lane.
// Model (fits r1-r16): per-CU shared units bind -- TA/L1 services each wave
// VMEM instruction ~30cyc, DS pipe services every __shfl ~5cyc for all 4
// SIMDs. All prior versions kept (VMEM*30 + DS*5)/CU ~ constant. v17 halves
// BOTH per element: 4 cols/lane -> half the waves (same float4 bytes/lane),
// and the emit tree yields 4 outputs per 30 shuffles (vs 2 per 20).
// Structure: v13 verbatim otherwise -- RB=8, deep E-prefetch (6 rows ahead),
// X-reload pipeline depth 4, XCD-chunked swizzle, no LDS, no occupancy attrs
// (they pin VGPR=64 and spill; v14 proved 108 VGPR spill-free without them).
// Derivatives unscaled (8fx,8fy,4ft); exact x2 rescale folded into u,v.

constexpr int IH  = 2048;
constexpr int IW  = 2048;
constexpr int RAD = 7;
constexpr int WIN = 15;
constexpr int NT  = 64;               // 1 wave per block
constexpr int SW  = 224;              // output cols per block (4/lane, lanes 0..55)
constexpr int RB  = 8;                // output rows per block
constexpr int SCAN = RB + WIN - 1;    // 22 steps; entering product rows r0-7..r0+14
constexpr int NSTRIP = 10;            // ceil(2048/224); strip 9 emits 32 cols
constexpr int NBAND  = IH / RB;       // 256
constexpr int NXCD   = 8;
constexpr int CHUNK  = NBAND / NXCD;  // 32 bands per XCD per strip

// Per-row derived terms for this lane's 4 columns: sp = prev+next, dt = next-prev.
struct Row { float sp[4]; float dt[4]; };

template<bool YE>
__device__ __forceinline__ Row load_row(const float* __restrict__ P,
                                        const float* __restrict__ N,
                                        int row, int pcb, bool lload) {
    if constexpr (YE) row = row < 0 ? 0 : (row > IH - 1 ? IH - 1 : row);
    float4 q = make_float4(0.f, 0.f, 0.f, 0.f), r = q;
    if (lload) {                       // false only for fully-OOB lanes (edges)
        const size_t off = (size_t)row * IW + pcb;
        q = *reinterpret_cast<const float4*>(P + off);   // pcb % 4 == 0: aligned
        r = *reinterpret_cast<const float4*>(N + off);
    }
    Row R;
    R.sp[0] = q.x + r.x; R.dt[0] = r.x - q.x;
    R.sp[1] = q.y + r.y; R.dt[1] = r.y - q.y;
    R.sp[2] = q.z + r.z; R.dt[2] = r.z - q.z;
    R.sp[3] = q.w + r.w; R.dt[3] = r.w - q.w;
    return R;
}

// Add (SUB=false) or remove (SUB=true) product-row pair (A=row r, B=row r+1).
// Lane owns product cols pcb..pcb+3; col pcb+4 terms come from lane t+1.
template<bool SUB, bool XE>
__device__ __forceinline__ void accum(float V[5][4], const Row& A, const Row& B,
                                      int t, bool ok, bool rep4) {
    float g[5], m[5], e[5];
    #pragma unroll
    for (int c = 0; c < 4; ++c) {
        g[c] = A.sp[c] + B.sp[c];   // -> 8*fx via horizontal diff
        m[c] = B.sp[c] - A.sp[c];   // -> 8*fy
        e[c] = A.dt[c] + B.dt[c];   // -> 4*ft
    }
    float g4 = __shfl(g[0], t + 1);   // lane63 wrap harmless: nothing reads it
    float m4 = __shfl(m[0], t + 1);
    float e4 = __shfl(e[0], t + 1);
    if constexpr (XE) {               // right edge: replicate own last col
        g4 = rep4 ? g[3] : g4; m4 = rep4 ? m[3] : m4; e4 = rep4 ? e[3] : e4;
    }
    g[4] = g4; m[4] = m4; e[4] = e4;
    #pragma unroll
    for (int c = 0; c < 4; ++c) {
        float fx = g[c + 1] - g[c];
        float fy = m[c] + m[c + 1];
        float ft = e[c] + e[c + 1];
        if constexpr (XE) {           // zero products outside the image
            fx = ok ? fx : 0.f; fy = ok ? fy : 0.f; ft = ok ? ft : 0.f;
        }
        if constexpr (!SUB) {
            V[0][c] += fx * fx; V[1][c] += fx * fy; V[2][c] += fy * fy;
            V[3][c] += fx * ft; V[4][c] += fy * ft;
        } else {
            V[0][c] -= fx * fx; V[1][c] -= fx * fy; V[2][c] -= fy * fy;
            V[3][c] -= fx * ft; V[4][c] -= fy * ft;
        }
    }
}

template<bool XE, bool YE>
__device__ __forceinline__ void lk_body(const float* __restrict__ P,
                                        const float* __restrict__ N,
                                        float* __restrict__ out,
                                        int c0, int r0, int t) {
    const int pcb = c0 - 8 + 4 * t;     // lane's first tracked col (mult of 4)
    bool ok = true, rep4 = false;
    if constexpr (XE) {
        // IW % 4 == 0 and pcb % 4 == 0 -> each lane fully in or fully out
        ok   = ((unsigned)pcb < (unsigned)IW);
        rep4 = (pcb + 4 >= IW) && ok;   // col pcb+4 outside-right: replicate
    }
    const bool lload = ok;              // interior strips: uniformly true

    float V[5][4] = {};

    // entering pipeline E0..E5 = rows r0-7 .. r0-2 (use distance 4-6 steps)
    Row E0 = load_row<YE>(P, N, r0 - 7, pcb, lload);
    Row E1 = load_row<YE>(P, N, r0 - 6, pcb, lload);
    Row E2 = load_row<YE>(P, N, r0 - 5, pcb, lload);
    Row E3 = load_row<YE>(P, N, r0 - 4, pcb, lload);
    Row E4 = load_row<YE>(P, N, r0 - 3, pcb, lload);
    Row E5 = load_row<YE>(P, N, r0 - 2, pcb, lload);
    Row X0, X1, X2, X3;                 // exit-reload pipeline, depth 4

    #pragma unroll
    for (int sr = 0; sr < SCAN; ++sr) { // fully unrolled (v15: rolled is worse)
        const int pr = r0 - RAD + sr;   // entering product row

        // deep prefetch: entering row pr+6 (last needed image row = r0+15)
        Row nE, nX;
        const bool doE = (sr <= 16);
        if (doE) nE = load_row<YE>(P, N, pr + 6, pcb, lload);
        // exit reload: row r0+sr-18 (r0-7..r0), issued 3-4 steps before use
        const bool doX = (sr >= 11 && sr <= 18);
        if (doX) nX = load_row<YE>(P, N, r0 + sr - 18, pcb, lload);

        // add entering product row (rows pr, pr+1)
        bool enter_ok = true;
        if constexpr (YE) enter_ok = (pr >= 0) && (pr < IH);
        if (enter_ok) accum<false, XE>(V, E0, E1, t, ok, rep4);

        // subtract exiting product row (rows pr-15 = X0, pr-14 = X1)
        if (sr >= WIN) {
            bool exit_ok = true;
            if constexpr (YE) exit_ok = (pr - WIN) >= 0;
            if (exit_ok) accum<true, XE>(V, X0, X1, t, ok, rep4);
        }

        // emit output row i = r0 + sr - 14: 4 outputs/lane
        if (sr >= WIN - 1) {
            float a0[5], a1[5], a2[5], a3[5];
            #pragma unroll
            for (int p = 0; p < 5; ++p) {
                const float Pg = (V[p][0] + V[p][1]) + (V[p][2] + V[p][3]);
                const float s1 = __shfl(Pg, t + 1);     // 3 independent shfl
                const float s2 = __shfl(Pg, t + 2);
                const float s3 = __shfl(Pg, t + 3);
                const float S16 = (Pg + s1) + (s2 + s3);  // cols pcb..pcb+15
                const float q0 = __shfl(V[p][0], t + 4);  // col pcb+16
                const float q1 = __shfl(V[p][1], t + 4);  // col pcb+17
                const float q2 = __shfl(V[p][2], t + 4);  // col pcb+18
                a0[p] = S16 - V[p][0];                    // cols pcb+1 ..pcb+15
                a1[p] = a0[p] - V[p][1] + q0;             // cols pcb+2 ..pcb+16
                a2[p] = a1[p] - V[p][2] + q1;             // cols pcb+3 ..pcb+17
                a3[p] = a2[p] - V[p][3] + q2;             // cols pcb+4 ..pcb+18
            }
            const int i = r0 + sr - (WIN - 1);
            const int x = c0 + 4 * t;
            if ((4 * t < SW) && (x + 3 < IW)) {
                float4 qu, qv;
                float* uo = &qu.x; float* vo = &qv.x;
                const float* aa[4] = { a0, a1, a2, a3 };
                #pragma unroll
                for (int c = 0; c < 4; ++c) {
                    const float Axx = aa[c][0], Axy = aa[c][1], Ayy = aa[c][2];
                    const float bx = aa[c][3], by = aa[c][4];
                    const float det = Axx * Ayy - Axy * Axy;
                    const float rd  = __builtin_amdgcn_rcpf(det) * 2.0f;
                    const bool  k   = (det != 0.f);
                    uo[c] = k ? (Ayy * bx - Axy * by) * rd : 0.f;
                    vo[c] = k ? (Axx * by - Axy * bx) * rd : 0.f;
                }
                *reinterpret_cast<float4*>(out + (size_t)i * IW + x) = qu;
                *reinterpret_cast<float4*>(out + (size_t)IH * IW + (size_t)i * IW + x) = qv;
            }
        }

        // slides (register renames after full unroll)
        E0 = E1; E1 = E2; E2 = E3; E3 = E4; E4 = E5; if (doE) E5 = nE;
        if (sr == 11)      X0 = nX;
        else if (sr == 12) X1 = nX;
        else if (sr == 13) X2 = nX;
        else if (sr == 14) X3 = nX;
        else if (sr >= 15) { X0 = X1; X1 = X2; X2 = X3; if (sr <= 18) X3 = nX; }
    }
}

__global__ __launch_bounds__(NT)   // NO occupancy attrs: they pin VGPR=64 and spill
void lk_kernel(const float* __restrict__ Pimg, const float* __restrict__ Nimg,
               float* __restrict__ out) {
    // XCD-chunked swizzle: XCD (bid&7) owns 32 contiguous 8-row bands of one
    // strip -> vertical-halo re-reads hit the local L2. 2560 % 8 == 0.
    const int bid   = blockIdx.x;
    const int xcd   = bid & 7;
    const int idx   = bid >> 3;               // 0..319
    const int strip = idx / CHUNK;            // 0..9
    const int pos   = idx % CHUNK;
    const int band  = xcd * CHUNK + pos;      // 0..255
    const int c0 = strip * SW;
    const int r0 = band * RB;
    const int t  = threadIdx.x;
    const bool xe = (strip == 0) || (strip == NSTRIP - 1);
    // rows touched: [r0-7, r0+15]; in-bounds iff 1 <= band <= NBAND-2
    const bool ye = (band == 0) || (band == NBAND - 1);
    if (!xe && !ye)      lk_body<false, false>(Pimg, Nimg, out, c0, r0, t);
    else if (xe && !ye)  lk_body<true,  false>(Pimg, Nimg, out, c0, r0, t);
    else if (!xe)        lk_body<false, true >(Pimg, Nimg, out, c0, r0, t);
    else                 lk_body<true,  true >(Pimg, Nimg, out, c0, r0, t);
}

extern "C" void kernel_launch(void* const* d_in, const int* in_sizes, int n_in,
                              void* d_out, int out_size, void* d_ws, size_t ws_size,
                              hipStream_t stream) {
    (void)in_sizes; (void)n_in; (void)d_ws; (void)ws_size; (void)out_size;
    const float* prev = (const float*)d_in[0];
    const float* nxt  = (const float*)d_in[1];
    float* out        = (float*)d_out;
    dim3 grid(NSTRIP * NBAND);                // 2560 one-wave blocks
    dim3 block(NT);
    hipLaunchKernelGGL(lk_kernel, grid, block, 0, stream, prev, nxt, out);
}

// Round 18
// 30.578 us; speedup vs baseline: 1.3370x; 1.3370x over previous
//
#include <hip/hip_runtime.h>

// Lucas-Kanade optical flow v18 = v13 + pre-shuffled col-2 cache + E-depth 7.
// v17 falsified the shared-unit model (fewer waves hurt 24%). Equilibrium
// model: per-wave dependency stalls at ~19 waves/CU saturation. Last on-path
// latency: 3 chained ds_bpermutes inside each accum (2 accums/step), awaited
// in-step. v18 hoists them: each row's sp0/dt0 is shuffled ONCE when the row
// is loaded/slid (a full step before use, latency covered), cached 2-deep
// for the enter and exit pipelines; accum builds g4/m4/e4 with 3 adds.
// Per-step new shuffles 6 -> 4, all off the critical path. E-depth 7.
// Otherwise v13 verbatim: RB=8, 4864 one-wave blocks, XCD-chunked swizzle,
// X-reload pipeline depth 5, prefix-doubling emit, 2 cols/lane, no
// occupancy attrs (they pin VGPR=64 and spill).
// Derivatives unscaled (8fx,8fy,4ft); exact x2 rescale folded into u,v.

constexpr int IH  = 2048;
constexpr int IW  = 2048;
constexpr int RAD = 7;
constexpr int WIN = 15;
constexpr int NT  = 64;               // 1 wave per block
constexpr int SW  = 112;              // output columns per block (2/lane, lanes 0..55)
constexpr int RB  = 8;                // output rows per block
constexpr int SCAN = RB + WIN - 1;    // 22 steps; entering product rows r0-7 .. r0+14
constexpr int NSTRIP = 19;            // 19*112 = 2128 >= 2048
constexpr int NBAND  = IH / RB;       // 256
constexpr int NXCD   = 8;
constexpr int CHUNK  = NBAND / NXCD;  // 32 bands per XCD per strip

// Per-row derived terms for this lane's 2 columns: sp = prev+next, dt = next-prev.
struct Row { float sp0, sp1, dt0, dt1; };

template<bool YE>
__device__ __forceinline__ Row load_row(const float* __restrict__ P,
                                        const float* __restrict__ N,
                                        int row, int pcb, bool lload) {
    if constexpr (YE) row = row < 0 ? 0 : (row > IH - 1 ? IH - 1 : row);
    float2 q = make_float2(0.f, 0.f), r = q;
    if (lload) {                       // false only for OOB lanes on edge strips
        const size_t off = (size_t)row * IW + pcb;
        q = *reinterpret_cast<const float2*>(P + off);   // 8B aligned (pcb even)
        r = *reinterpret_cast<const float2*>(N + off);
    }
    Row R;
    R.sp0 = q.x + r.x; R.dt0 = r.x - q.x;
    R.sp1 = q.y + r.y; R.dt1 = r.y - q.y;
    return R;
}

// Col-2 (neighbor-lane) terms for one row, shuffled ONCE at load/slide time.
struct Sh { float sp4, dt4; };

template<bool XE>
__device__ __forceinline__ Sh mksh(const Row& R, int t, bool rep2) {
    Sh s;
    s.sp4 = __shfl(R.sp0, t + 1);     // lane63 wrap feeds only untracked col
    s.dt4 = __shfl(R.dt0, t + 1);
    if constexpr (XE) {               // right edge: replicate own last column
        s.sp4 = rep2 ? R.sp1 : s.sp4;
        s.dt4 = rep2 ? R.dt1 : s.dt4;
    }
    return s;
}

// Add (SUB=false) or remove (SUB=true) product-row pair (A=row r, B=row r+1),
// with pre-shuffled col-2 terms for A and B.
template<bool SUB, bool XE>
__device__ __forceinline__ void accum(float V[5][2], const Row& A, const Row& B,
                                      const Sh& sa, const Sh& sb, bool ok) {
    const float g0 = A.sp0 + B.sp0, g1 = A.sp1 + B.sp1;  // -> 8*fx via horiz diff
    const float m0 = B.sp0 - A.sp0, m1 = B.sp1 - A.sp1;  // -> 8*fy
    const float e0 = A.dt0 + B.dt0, e1 = A.dt1 + B.dt1;  // -> 4*ft
    const float g2 = sa.sp4 + sb.sp4;                    // col-2 terms, no shfl
    const float m2 = sb.sp4 - sa.sp4;
    const float e2 = sa.dt4 + sb.dt4;
    float fx0 = g1 - g0, fy0 = m0 + m1, ft0 = e0 + e1;
    float fx1 = g2 - g1, fy1 = m1 + m2, ft1 = e1 + e2;
    if constexpr (XE) {                 // zero products outside the image
        fx0 = ok ? fx0 : 0.f; fy0 = ok ? fy0 : 0.f; ft0 = ok ? ft0 : 0.f;
        fx1 = ok ? fx1 : 0.f; fy1 = ok ? fy1 : 0.f; ft1 = ok ? ft1 : 0.f;
    }
    if constexpr (!SUB) {
        V[0][0] += fx0 * fx0; V[1][0] += fx0 * fy0; V[2][0] += fy0 * fy0;
        V[3][0] += fx0 * ft0; V[4][0] += fy0 * ft0;
        V[0][1] += fx1 * fx1; V[1][1] += fx1 * fy1; V[2][1] += fy1 * fy1;
        V[3][1] += fx1 * ft1; V[4][1] += fy1 * ft1;
    } else {
        V[0][0] -= fx0 * fx0; V[1][0] -= fx0 * fy0; V[2][0] -= fy0 * fy0;
        V[3][0] -= fx0 * ft0; V[4][0] -= fy0 * ft0;
        V[0][1] -= fx1 * fx1; V[1][1] -= fx1 * fy1; V[2][1] -= fy1 * fy1;
        V[3][1] -= fx1 * ft1; V[4][1] -= fy1 * ft1;
    }
}

template<bool XE, bool YE>
__device__ __forceinline__ void lk_body(const float* __restrict__ P,
                                        const float* __restrict__ N,
                                        float* __restrict__ out,
                                        int c0, int r0, int t) {
    const int pcb = c0 - 8 + 2 * t;     // lane's first tracked product column (even)
    bool ok = true, rep2 = false;
    if constexpr (XE) {
        ok   = ((unsigned)pcb < (unsigned)IW);   // both owned cols in image
        rep2 = (pcb + 2 >= IW) && ok;            // col pcb+2 replicates pcb+1
    }
    const bool lload = ok;              // interior strips: uniformly true

    float V[5][2] = {};

    // entering pipeline E0..E6 = rows r0-7 .. r0-1 (use distance 5-7 steps)
    Row E0 = load_row<YE>(P, N, r0 - 7, pcb, lload);
    Row E1 = load_row<YE>(P, N, r0 - 6, pcb, lload);
    Row E2 = load_row<YE>(P, N, r0 - 5, pcb, lload);
    Row E3 = load_row<YE>(P, N, r0 - 4, pcb, lload);
    Row E4 = load_row<YE>(P, N, r0 - 3, pcb, lload);
    Row E5 = load_row<YE>(P, N, r0 - 2, pcb, lload);
    Row E6 = load_row<YE>(P, N, r0 - 1, pcb, lload);
    Row X0, X1, X2, X3, X4;             // exit-reload pipeline, depth 5

    // pre-shuffled col-2 caches for the rows entering accum next
    Sh e0s = mksh<XE>(E0, t, rep2);
    Sh e1s = mksh<XE>(E1, t, rep2);
    Sh x0s, x1s;

    #pragma unroll
    for (int sr = 0; sr < SCAN; ++sr) { // fully unrolled: sr compile-time
        const int pr = r0 - RAD + sr;   // entering product row

        // deep prefetch: entering row pr+7 (last needed image row = r0+15)
        Row nE, nX;
        const bool doE = (sr <= 15);
        if (doE) nE = load_row<YE>(P, N, pr + 7, pcb, lload);
        const bool doX = (sr >= 10 && sr <= 17);  // row r0+sr-17: r0-7 .. r0
        if (doX) nX = load_row<YE>(P, N, r0 + sr - 17, pcb, lload);

        // add entering product row (rows pr = E0, pr+1 = E1)
        bool enter_ok = true;
        if constexpr (YE) enter_ok = (pr >= 0) && (pr < IH);
        if (enter_ok) accum<false, XE>(V, E0, E1, e0s, e1s, ok);
        // roll the enter shuffle-cache: next step's pair = (E1, E2)
        e0s = e1s; e1s = mksh<XE>(E2, t, rep2);

        // subtract exiting product row (rows pr-15 = X0, pr-14 = X1)
        if (sr >= WIN) {
            bool exit_ok = true;
            if constexpr (YE) exit_ok = (pr - WIN) >= 0;
            if (exit_ok) accum<true, XE>(V, X0, X1, x0s, x1s, ok);
        }
        // build/roll the exit shuffle-cache (X0 set at sr=10, X1 at 11, ...)
        if (sr == 13)      x0s = mksh<XE>(X0, t, rep2);
        else if (sr == 14) x1s = mksh<XE>(X1, t, rep2);
        else if (sr >= 15 && sr < SCAN - 1) { x0s = x1s; x1s = mksh<XE>(X2, t, rep2); }

        // emit output row i = r0 + sr - 14
        if (sr >= WIN - 1) {
            float a0[5], a1[5];
            #pragma unroll
            for (int p = 0; p < 5; ++p) {
                const float Pg = V[p][0] + V[p][1];        // pair sum (2 cols)
                float S = Pg + __shfl(Pg, t + 1);
                S += __shfl(S, t + 2);
                S += __shfl(S, t + 4);                     // cols pcb..pcb+15
                const float q0 = __shfl(V[p][0], t + 8);   // col pcb+16
                a0[p] = S - V[p][0];                       // cols pcb+1 .. pcb+15
                a1[p] = (S - Pg) + q0;                     // cols pcb+2 .. pcb+16
            }
            const float det0 = a0[0] * a0[2] - a0[1] * a0[1];
            const float rd0  = __builtin_amdgcn_rcpf(det0) * 2.0f;  // fold scale
            const bool  k0   = (det0 != 0.f);
            const float det1 = a1[0] * a1[2] - a1[1] * a1[1];
            const float rd1  = __builtin_amdgcn_rcpf(det1) * 2.0f;
            const bool  k1   = (det1 != 0.f);
            float2 qu, qv;
            qu.x = k0 ? (a0[2] * a0[3] - a0[1] * a0[4]) * rd0 : 0.f;
            qv.x = k0 ? (a0[0] * a0[4] - a0[1] * a0[3]) * rd0 : 0.f;
            qu.y = k1 ? (a1[2] * a1[3] - a1[1] * a1[4]) * rd1 : 0.f;
            qv.y = k1 ? (a1[0] * a1[4] - a1[1] * a1[3]) * rd1 : 0.f;

            const int i  = r0 + sr - (WIN - 1);
            const int x0 = c0 + 2 * t;
            if ((2 * t < SW) && (x0 < IW)) {   // x0 even -> x0+1 in range too
                *reinterpret_cast<float2*>(out + (size_t)i * IW + x0) = qu;
                *reinterpret_cast<float2*>(out + (size_t)IH * IW + (size_t)i * IW + x0) = qv;
            }
        }

        // slides (register renames after full unroll)
        E0 = E1; E1 = E2; E2 = E3; E3 = E4; E4 = E5; E5 = E6; if (doE) E6 = nE;
        if (sr == 10)      X0 = nX;
        else if (sr == 11) X1 = nX;
        else if (sr == 12) X2 = nX;
        else if (sr == 13) X3 = nX;
        else if (sr == 14) X4 = nX;
        else if (sr >= 15) { X0 = X1; X1 = X2; X2 = X3; X3 = X4; if (sr <= 17) X4 = nX; }
    }
}

__global__ __launch_bounds__(NT)   // NO occupancy attrs: they pin VGPR=64 and spill
void lk_kernel(const float* __restrict__ Pimg, const float* __restrict__ Nimg,
               float* __restrict__ out) {
    // XCD-chunked swizzle: XCD (bid&7) owns 32 contiguous 8-row bands of one
    // strip -> vertical-halo re-reads hit the local L2.
    const int bid   = blockIdx.x;
    const int xcd   = bid & 7;
    const int idx   = bid >> 3;               // 0..607
    const int strip = idx / CHUNK;            // 0..18
    const int pos   = idx % CHUNK;
    const int band  = xcd * CHUNK + pos;      // 0..255
    const int c0 = strip * SW;
    const int r0 = band * RB;
    const int t  = threadIdx.x;
    const bool xe = (strip == 0) || (strip == NSTRIP - 1);
    // rows touched: [r0-7, r0+15]; in-bounds iff 1 <= band <= NBAND-2
    const bool ye = (band == 0) || (band == NBAND - 1);
    if (!xe && !ye)      lk_body<false, false>(Pimg, Nimg, out, c0, r0, t);
    else if (xe && !ye)  lk_body<true,  false>(Pimg, Nimg, out, c0, r0, t);
    else if (!xe)        lk_body<false, true >(Pimg, Nimg, out, c0, r0, t);
    else                 lk_body<true,  true >(Pimg, Nimg, out, c0, r0, t);
}

extern "C" void kernel_launch(void* const* d_in, const int* in_sizes, int n_in,
                              void* d_out, int out_size, void* d_ws, size_t ws_size,
                              hipStream_t stream) {
    (void)in_sizes; (void)n_in; (void)d_ws; (void)ws_size; (void)out_size;
    const float* prev = (const float*)d_in[0];
    const float* nxt  = (const float*)d_in[1];
    float* out        = (float*)d_out;
    dim3 grid(NSTRIP * NBAND);                // 4864 one-wave blocks
    dim3 block(NT);
    hipLaunchKernelGGL(lk_kernel, grid, block, 0, stream, prev, nxt, out);
}